// Round 1
// baseline (596.230 us; speedup 1.0000x reference)
//
#include <hip/hip_runtime.h>

typedef _Float16 half8 __attribute__((ext_vector_type(8)));
typedef float f32x4 __attribute__((ext_vector_type(4)));

static constexpr int D = 1024;       // VQ_C == C_IN
static constexpr int NCODE = 2048;   // codebook size
static constexpr int MTOK = 16384;   // B * L = 8 * 2048
static constexpr int KIN = 2048;     // C_IN * DS
static constexpr int TLEN = 4096;

__device__ __forceinline__ void gload16(const void* g, void* l) {
  __builtin_amdgcn_global_load_lds(
      (const __attribute__((address_space(1))) void*)g,
      (__attribute__((address_space(3))) void*)l, 16, 0, 0);
}

// ---------------- pack kernels ----------------
// x [B, C_IN, T] -> token-major rows [M=16384, K=2048], split hi/lo f16.
__global__ __launch_bounds__(256) void k_pack_x(const float* __restrict__ x,
                                                _Float16* __restrict__ xh,
                                                _Float16* __restrict__ xl) {
  __shared__ float lds[32][65];
  const int tt0 = blockIdx.x * 64;   // t-tile
  const int cc0 = blockIdx.y * 32;   // c-tile
  const int b = blockIdx.z;
  const float* xb = x + ((size_t)b * D + cc0) * TLEN + tt0;
#pragma unroll
  for (int i = 0; i < 8; ++i) {
    int idx = threadIdx.x + i * 256;
    lds[idx >> 6][idx & 63] = xb[(size_t)(idx >> 6) * TLEN + (idx & 63)];
  }
  __syncthreads();
  const size_t mrow0 = (size_t)b * 2048 + (tt0 >> 1);
#pragma unroll
  for (int i = 0; i < 8; ++i) {
    int idx = threadIdx.x + i * 256;
    int r = idx >> 6, kk = idx & 63;            // r = local token row, kk = local k
    float v = lds[kk >> 1][2 * r + (kk & 1)];   // k = 2c + s  ->  x[c][2l+s]
    _Float16 h = (_Float16)v;
    size_t off = (mrow0 + r) * (size_t)KIN + (size_t)cc0 * 2 + kk;
    xh[off] = h;
    xl[off] = (_Float16)(v - (float)h);
  }
}

__global__ __launch_bounds__(256) void k_split(const float* __restrict__ s,
                                               _Float16* __restrict__ hi,
                                               _Float16* __restrict__ lo, int n) {
  int i = blockIdx.x * 256 + threadIdx.x;
  if (i < n) {
    float v = s[i];
    _Float16 h = (_Float16)v;
    hi[i] = h;
    lo[i] = (_Float16)(v - (float)h);
  }
}

__global__ __launch_bounds__(256) void k_tohalf(const float* __restrict__ s,
                                                _Float16* __restrict__ hi, int n) {
  int i = blockIdx.x * 256 + threadIdx.x;
  if (i < n) hi[i] = (_Float16)s[i];
}

// ||embed_row||^2 - 1024 in f64, stored f32 (centered so later f32 combine is precise)
__global__ __launch_bounds__(256) void k_e2(const float* __restrict__ embed,
                                            float* __restrict__ e2c) {
  int row = blockIdx.x * 4 + (threadIdx.x >> 6);
  int lane = threadIdx.x & 63;
  const float* er = embed + (size_t)row * D;
  double s = 0.0;
  for (int i = lane; i < D; i += 64) { double v = er[i]; s += v * v; }
#pragma unroll
  for (int mk = 1; mk < 64; mk <<= 1) s += __shfl_xor(s, mk, 64);
  if (lane == 0) e2c[row] = (float)(s - 1024.0);
}

// ---------------- GEMM A: tokens = Xs * Ws^T (f16x2 split, 3 products) ----------------
__global__ __launch_bounds__(256) void k_gemm_tok(
    const _Float16* __restrict__ xh, const _Float16* __restrict__ xl,
    const _Float16* __restrict__ wh, const _Float16* __restrict__ wl,
    const float* __restrict__ b_in,
    _Float16* __restrict__ tokh, _Float16* __restrict__ tokl,
    float* __restrict__ t2) {
  __shared__ _Float16 sAh[128 * 32], sAl[128 * 32], sBh[128 * 32], sBl[128 * 32];
  const int n0 = blockIdx.x * 128, m0 = blockIdx.y * 128;
  const int tid = threadIdx.x, lane = tid & 63, w = tid >> 6;
  const int wr = w >> 1, wc = w & 1, lr = lane & 15, lk = lane >> 4;
  f32x4 acc[4][4] = {};

  const int g0 = w * 128 + lane, g1 = g0 + 64;
  const int rA0 = g0 >> 2, cA0 = g0 & 3, rA1 = g1 >> 2, cA1 = g1 & 3;
  const int lb0 = (w * 128) * 16, lb1 = (w * 128 + 64) * 16;  // wave-uniform LDS byte bases

  for (int kt = 0; kt < KIN / 32; ++kt) {
    const int k0 = kt * 32;
    gload16(xh + (size_t)(m0 + rA0) * KIN + k0 + cA0 * 8, (char*)sAh + lb0);
    gload16(xh + (size_t)(m0 + rA1) * KIN + k0 + cA1 * 8, (char*)sAh + lb1);
    gload16(xl + (size_t)(m0 + rA0) * KIN + k0 + cA0 * 8, (char*)sAl + lb0);
    gload16(xl + (size_t)(m0 + rA1) * KIN + k0 + cA1 * 8, (char*)sAl + lb1);
    gload16(wh + (size_t)(n0 + rA0) * KIN + k0 + cA0 * 8, (char*)sBh + lb0);
    gload16(wh + (size_t)(n0 + rA1) * KIN + k0 + cA1 * 8, (char*)sBh + lb1);
    gload16(wl + (size_t)(n0 + rA0) * KIN + k0 + cA0 * 8, (char*)sBl + lb0);
    gload16(wl + (size_t)(n0 + rA1) * KIN + k0 + cA1 * 8, (char*)sBl + lb1);
    __syncthreads();
    half8 ah[4], al[4], bh[4], bl[4];
#pragma unroll
    for (int f = 0; f < 4; ++f) {
      ah[f] = *(const half8*)(sAh + (wr * 64 + f * 16 + lr) * 32 + lk * 8);
      al[f] = *(const half8*)(sAl + (wr * 64 + f * 16 + lr) * 32 + lk * 8);
      bh[f] = *(const half8*)(sBh + (wc * 64 + f * 16 + lr) * 32 + lk * 8);
      bl[f] = *(const half8*)(sBl + (wc * 64 + f * 16 + lr) * 32 + lk * 8);
    }
#pragma unroll
    for (int fm = 0; fm < 4; ++fm)
#pragma unroll
      for (int fn = 0; fn < 4; ++fn) {
        acc[fm][fn] = __builtin_amdgcn_mfma_f32_16x16x32_f16(ah[fm], bh[fn], acc[fm][fn], 0, 0, 0);
        acc[fm][fn] = __builtin_amdgcn_mfma_f32_16x16x32_f16(ah[fm], bl[fn], acc[fm][fn], 0, 0, 0);
        acc[fm][fn] = __builtin_amdgcn_mfma_f32_16x16x32_f16(al[fm], bh[fn], acc[fm][fn], 0, 0, 0);
      }
    __syncthreads();
  }
  // epilogue: +b_in, split to f16 hi/lo, accumulate ||t||^2 per token row
#pragma unroll
  for (int fm = 0; fm < 4; ++fm) {
#pragma unroll
    for (int j = 0; j < 4; ++j) {
      int row = wr * 64 + fm * 16 + lk * 4 + j;
      size_t m = (size_t)m0 + row;
      float v2 = 0.f;
#pragma unroll
      for (int fn = 0; fn < 4; ++fn) {
        int col = n0 + wc * 64 + fn * 16 + lr;
        float v = acc[fm][fn][j] + b_in[col];
        v2 += v * v;
        _Float16 h = (_Float16)v;
        tokh[m * D + col] = h;
        tokl[m * D + col] = (_Float16)(v - (float)h);
      }
#pragma unroll
      for (int mk = 1; mk < 16; mk <<= 1) v2 += __shfl_xor(v2, mk, 64);
      if (lr == 0) atomicAdd(&t2[m], v2);
    }
  }
}

// ---------------- GEMM B: scores + fused argmin ----------------
__global__ __launch_bounds__(256) void k_gemm_score(
    const _Float16* __restrict__ tokh, const _Float16* __restrict__ tokl,
    const _Float16* __restrict__ eh, const _Float16* __restrict__ el,
    const float* __restrict__ e2c, unsigned long long* __restrict__ keys) {
  __shared__ _Float16 sAh[128 * 32], sAl[128 * 32], sBh[128 * 32], sBl[128 * 32];
  const int n0 = blockIdx.x * 128, m0 = blockIdx.y * 128;
  const int tid = threadIdx.x, lane = tid & 63, w = tid >> 6;
  const int wr = w >> 1, wc = w & 1, lr = lane & 15, lk = lane >> 4;
  f32x4 acc[4][4] = {};

  const int g0 = w * 128 + lane, g1 = g0 + 64;
  const int rA0 = g0 >> 2, cA0 = g0 & 3, rA1 = g1 >> 2, cA1 = g1 & 3;
  const int lb0 = (w * 128) * 16, lb1 = (w * 128 + 64) * 16;

  for (int kt = 0; kt < D / 32; ++kt) {
    const int k0 = kt * 32;
    gload16(tokh + (size_t)(m0 + rA0) * D + k0 + cA0 * 8, (char*)sAh + lb0);
    gload16(tokh + (size_t)(m0 + rA1) * D + k0 + cA1 * 8, (char*)sAh + lb1);
    gload16(tokl + (size_t)(m0 + rA0) * D + k0 + cA0 * 8, (char*)sAl + lb0);
    gload16(tokl + (size_t)(m0 + rA1) * D + k0 + cA1 * 8, (char*)sAl + lb1);
    gload16(eh + (size_t)(n0 + rA0) * D + k0 + cA0 * 8, (char*)sBh + lb0);
    gload16(eh + (size_t)(n0 + rA1) * D + k0 + cA1 * 8, (char*)sBh + lb1);
    gload16(el + (size_t)(n0 + rA0) * D + k0 + cA0 * 8, (char*)sBl + lb0);
    gload16(el + (size_t)(n0 + rA1) * D + k0 + cA1 * 8, (char*)sBl + lb1);
    __syncthreads();
    half8 ah[4], al[4], bh[4], bl[4];
#pragma unroll
    for (int f = 0; f < 4; ++f) {
      ah[f] = *(const half8*)(sAh + (wr * 64 + f * 16 + lr) * 32 + lk * 8);
      al[f] = *(const half8*)(sAl + (wr * 64 + f * 16 + lr) * 32 + lk * 8);
      bh[f] = *(const half8*)(sBh + (wc * 64 + f * 16 + lr) * 32 + lk * 8);
      bl[f] = *(const half8*)(sBl + (wc * 64 + f * 16 + lr) * 32 + lk * 8);
    }
#pragma unroll
    for (int fm = 0; fm < 4; ++fm)
#pragma unroll
      for (int fn = 0; fn < 4; ++fn) {
        acc[fm][fn] = __builtin_amdgcn_mfma_f32_16x16x32_f16(ah[fm], bh[fn], acc[fm][fn], 0, 0, 0);
        acc[fm][fn] = __builtin_amdgcn_mfma_f32_16x16x32_f16(ah[fm], bl[fn], acc[fm][fn], 0, 0, 0);
        acc[fm][fn] = __builtin_amdgcn_mfma_f32_16x16x32_f16(al[fm], bh[fn], acc[fm][fn], 0, 0, 0);
      }
    __syncthreads();
  }
  // epilogue: mval = (||e||^2 - 1024) - 2*score; block-local argmin -> packed atomicMin
#pragma unroll
  for (int fm = 0; fm < 4; ++fm) {
#pragma unroll
    for (int j = 0; j < 4; ++j) {
      int row = wr * 64 + fm * 16 + lk * 4 + j;
      size_t m = (size_t)m0 + row;
      float best = 3.4e38f;
      int bidx = 0x7FFFFFFF;
#pragma unroll
      for (int fn = 0; fn < 4; ++fn) {
        int col = n0 + wc * 64 + fn * 16 + lr;
        float mv = e2c[col] - 2.0f * acc[fm][fn][j];
        if (mv < best) { best = mv; bidx = col; }
      }
#pragma unroll
      for (int mk = 1; mk < 16; mk <<= 1) {
        float ob = __shfl_xor(best, mk, 64);
        int oi = __shfl_xor(bidx, mk, 64);
        if (ob < best || (ob == best && oi < bidx)) { best = ob; bidx = oi; }
      }
      if (lr == 0) {
        unsigned ub = __float_as_uint(best);
        ub = (ub & 0x80000000u) ? ~ub : (ub | 0x80000000u);  // monotone f32->u32
        unsigned long long key = ((unsigned long long)ub << 32) | (unsigned)bidx;
        atomicMin(&keys[m], key);
      }
    }
  }
}

// ---------------- GEMM C: out = embed[idx] * w_out^T, duplicated to 2 timesteps ----------------
__global__ __launch_bounds__(256) void k_gemm_out(
    const _Float16* __restrict__ eh, const unsigned long long* __restrict__ keys,
    const _Float16* __restrict__ woh, const float* __restrict__ b_out,
    const float* __restrict__ mask, float* __restrict__ out) {
  __shared__ _Float16 sA[128 * 32], sB[128 * 32];
  __shared__ float sC[32 * 129];
  const int n0 = blockIdx.x * 128, m0 = blockIdx.y * 128;
  const int tid = threadIdx.x, lane = tid & 63, w = tid >> 6;
  const int wr = w >> 1, wc = w & 1, lr = lane & 15, lk = lane >> 4;
  f32x4 acc[4][4] = {};

  const int g0 = w * 128 + lane, g1 = g0 + 64;
  const int rA0 = g0 >> 2, cA0 = g0 & 3, rA1 = g1 >> 2, cA1 = g1 & 3;
  const int lb0 = (w * 128) * 16, lb1 = (w * 128 + 64) * 16;
  const unsigned i0 = (unsigned)(keys[m0 + rA0] & 0xFFFFFFFFull);
  const unsigned i1 = (unsigned)(keys[m0 + rA1] & 0xFFFFFFFFull);
  const _Float16* srcA0 = eh + (size_t)i0 * D + cA0 * 8;
  const _Float16* srcA1 = eh + (size_t)i1 * D + cA1 * 8;

  for (int kt = 0; kt < D / 32; ++kt) {
    const int k0 = kt * 32;
    gload16(srcA0 + k0, (char*)sA + lb0);
    gload16(srcA1 + k0, (char*)sA + lb1);
    gload16(woh + (size_t)(n0 + rA0) * D + k0 + cA0 * 8, (char*)sB + lb0);
    gload16(woh + (size_t)(n0 + rA1) * D + k0 + cA1 * 8, (char*)sB + lb1);
    __syncthreads();
    half8 a[4], b[4];
#pragma unroll
    for (int f = 0; f < 4; ++f) {
      a[f] = *(const half8*)(sA + (wr * 64 + f * 16 + lr) * 32 + lk * 8);
      b[f] = *(const half8*)(sB + (wc * 64 + f * 16 + lr) * 32 + lk * 8);
    }
#pragma unroll
    for (int fm = 0; fm < 4; ++fm)
#pragma unroll
      for (int fn = 0; fn < 4; ++fn)
        acc[fm][fn] = __builtin_amdgcn_mfma_f32_16x16x32_f16(a[fm], b[fn], acc[fm][fn], 0, 0, 0);
    __syncthreads();
  }
  // epilogue: transpose via LDS; write each token value to t=2l and 2l+1 (coalesced in t)
  for (int ch = 0; ch < 4; ++ch) {
    __syncthreads();
    if (wr == (ch >> 1)) {
      int fb = (ch & 1) * 2;
#pragma unroll
      for (int f2 = 0; f2 < 2; ++f2) {
        int fm = fb + f2;
#pragma unroll
        for (int fn = 0; fn < 4; ++fn)
#pragma unroll
          for (int j = 0; j < 4; ++j) {
            int lrow = f2 * 16 + lk * 4 + j;
            int col = wc * 64 + fn * 16 + lr;
            sC[lrow * 129 + col] = acc[fm][fn][j] + b_out[n0 + col];
          }
      }
    }
    __syncthreads();
    const int mbase = m0 + ch * 32;
    const int b = mbase >> 11;          // batch
    const int l0 = mbase & 2047;        // token within batch
    const float mval = mask[(size_t)b * TLEN + 2 * l0 + lane];
    for (int oo = 0; oo < 32; ++oo) {
      int ocol = w * 32 + oo;
      float v = sC[(lane >> 1) * 129 + ocol];
      out[((size_t)(b * D + n0 + ocol)) * TLEN + 2 * l0 + lane] = v * mval;
    }
  }
}

// ---------------- loss ----------------
__global__ __launch_bounds__(256) void k_loss(const unsigned long long* __restrict__ keys,
                                              const float* __restrict__ t2,
                                              double* __restrict__ acc) {
  int m = blockIdx.x * 256 + threadIdx.x;
  unsigned long long k = keys[m];
  unsigned u = (unsigned)(k >> 32);
  unsigned bits = (u & 0x80000000u) ? (u & 0x7FFFFFFFu) : ~u;
  float mval = __uint_as_float(bits);            // (||e*||^2 - 1024) - 2*s*
  double c = (double)mval + 1024.0 + (double)t2[m];
#pragma unroll
  for (int mk = 1; mk < 64; mk <<= 1) c += __shfl_xor(c, mk, 64);
  __shared__ double part[4];
  if ((threadIdx.x & 63) == 0) part[threadIdx.x >> 6] = c;
  __syncthreads();
  if (threadIdx.x == 0) atomicAdd(acc, part[0] + part[1] + part[2] + part[3]);
}

__global__ void k_finalize(const double* __restrict__ acc, float* __restrict__ dst) {
  if (threadIdx.x == 0 && blockIdx.x == 0) *dst = (float)(*acc * (1.0 / 16777216.0));
}

// ---------------- host ----------------
extern "C" void kernel_launch(void* const* d_in, const int* in_sizes, int n_in,
                              void* d_out, int out_size, void* d_ws, size_t ws_size,
                              hipStream_t stream) {
  (void)in_sizes; (void)n_in; (void)out_size;
  const float* x      = (const float*)d_in[0];
  const float* xmask  = (const float*)d_in[1];
  const float* w_in   = (const float*)d_in[2];
  const float* b_in   = (const float*)d_in[3];
  const float* embed  = (const float*)d_in[4];
  const float* w_out  = (const float*)d_in[5];
  const float* b_out  = (const float*)d_in[6];
  float* out = (float*)d_out;

  // x hi/lo splits live in d_out (dead until k_gemm_out overwrites it)
  _Float16* xh = (_Float16*)d_out;
  _Float16* xl = xh + (size_t)MTOK * KIN;   // 33,554,432 elems each = exactly out[0..33554431]

  char* p = (char*)d_ws;
  auto take = [&](size_t sz) { char* r = p; p += (sz + 255) & ~(size_t)255; return r; };
  _Float16* wh   = (_Float16*)take((size_t)D * KIN * 2);
  _Float16* wl   = (_Float16*)take((size_t)D * KIN * 2);
  _Float16* eh   = (_Float16*)take((size_t)NCODE * D * 2);
  _Float16* el   = (_Float16*)take((size_t)NCODE * D * 2);
  _Float16* woh  = (_Float16*)take((size_t)D * D * 2);
  float* e2c     = (float*)take((size_t)NCODE * 4);
  _Float16* tokh = (_Float16*)take((size_t)MTOK * D * 2);
  _Float16* tokl = (_Float16*)take((size_t)MTOK * D * 2);
  float* t2      = (float*)take((size_t)MTOK * 4);
  unsigned long long* keys = (unsigned long long*)take((size_t)MTOK * 8);
  double* lossacc = (double*)take(256);
  if ((size_t)(p - (char*)d_ws) > ws_size) return;  // visible failure if ws too small

  hipMemsetAsync(keys, 0xFF, (size_t)MTOK * 8, stream);
  hipMemsetAsync(t2, 0, (size_t)MTOK * 4, stream);
  hipMemsetAsync(lossacc, 0, 8, stream);

  k_pack_x<<<dim3(64, 32, 8), 256, 0, stream>>>(x, xh, xl);
  k_split<<<(D * KIN + 255) / 256, 256, 0, stream>>>(w_in, wh, wl, D * KIN);
  k_split<<<(NCODE * D + 255) / 256, 256, 0, stream>>>(embed, eh, el, NCODE * D);
  k_tohalf<<<(D * D + 255) / 256, 256, 0, stream>>>(w_out, woh, D * D);
  k_e2<<<NCODE / 4, 256, 0, stream>>>(embed, e2c);

  k_gemm_tok<<<dim3(D / 128, MTOK / 128), 256, 0, stream>>>(xh, xl, wh, wl, b_in, tokh, tokl, t2);
  k_gemm_score<<<dim3(NCODE / 128, MTOK / 128), 256, 0, stream>>>(tokh, tokl, eh, el, e2c, keys);
  k_gemm_out<<<dim3(D / 128, MTOK / 128), 256, 0, stream>>>(eh, keys, woh, b_out, xmask, out);

  k_loss<<<MTOK / 256, 256, 0, stream>>>(keys, t2, lossacc);
  k_finalize<<<1, 64, 0, stream>>>(lossacc, out + (size_t)MTOK * KIN);
}

// Round 2
// 568.670 us; speedup vs baseline: 1.0485x; 1.0485x over previous
//
#include <hip/hip_runtime.h>

typedef _Float16 half8 __attribute__((ext_vector_type(8)));
typedef float f32x4 __attribute__((ext_vector_type(4)));

static constexpr int D = 1024;       // VQ_C == C_IN
static constexpr int NCODE = 2048;   // codebook size
static constexpr int MTOK = 16384;   // B * L = 8 * 2048
static constexpr int KIN = 2048;     // C_IN * DS
static constexpr int TLEN = 4096;

__device__ __forceinline__ void gload16(const void* g, void* l) {
  __builtin_amdgcn_global_load_lds(
      (const __attribute__((address_space(1))) void*)g,
      (__attribute__((address_space(3))) void*)l, 16, 0, 0);
}

#define SBAR()   asm volatile("s_barrier" ::: "memory")
#define WAITV6() asm volatile("s_waitcnt vmcnt(6)" ::: "memory")
#define WAITV0() asm volatile("s_waitcnt vmcnt(0)" ::: "memory")

// ---------------- pack kernels (unchanged) ----------------
__global__ __launch_bounds__(256) void k_pack_x(const float* __restrict__ x,
                                                _Float16* __restrict__ xh,
                                                _Float16* __restrict__ xl) {
  __shared__ float lds[32][65];
  const int tt0 = blockIdx.x * 64;
  const int cc0 = blockIdx.y * 32;
  const int b = blockIdx.z;
  const float* xb = x + ((size_t)b * D + cc0) * TLEN + tt0;
#pragma unroll
  for (int i = 0; i < 8; ++i) {
    int idx = threadIdx.x + i * 256;
    lds[idx >> 6][idx & 63] = xb[(size_t)(idx >> 6) * TLEN + (idx & 63)];
  }
  __syncthreads();
  const size_t mrow0 = (size_t)b * 2048 + (tt0 >> 1);
#pragma unroll
  for (int i = 0; i < 8; ++i) {
    int idx = threadIdx.x + i * 256;
    int r = idx >> 6, kk = idx & 63;
    float v = lds[kk >> 1][2 * r + (kk & 1)];
    _Float16 h = (_Float16)v;
    size_t off = (mrow0 + r) * (size_t)KIN + (size_t)cc0 * 2 + kk;
    xh[off] = h;
    xl[off] = (_Float16)(v - (float)h);
  }
}

__global__ __launch_bounds__(256) void k_split(const float* __restrict__ s,
                                               _Float16* __restrict__ hi,
                                               _Float16* __restrict__ lo, int n) {
  int i = blockIdx.x * 256 + threadIdx.x;
  if (i < n) {
    float v = s[i];
    _Float16 h = (_Float16)v;
    hi[i] = h;
    lo[i] = (_Float16)(v - (float)h);
  }
}

__global__ __launch_bounds__(256) void k_tohalf(const float* __restrict__ s,
                                                _Float16* __restrict__ hi, int n) {
  int i = blockIdx.x * 256 + threadIdx.x;
  if (i < n) hi[i] = (_Float16)s[i];
}

__global__ __launch_bounds__(256) void k_e2(const float* __restrict__ embed,
                                            float* __restrict__ e2c) {
  int row = blockIdx.x * 4 + (threadIdx.x >> 6);
  int lane = threadIdx.x & 63;
  const float* er = embed + (size_t)row * D;
  double s = 0.0;
  for (int i = lane; i < D; i += 64) { double v = er[i]; s += v * v; }
#pragma unroll
  for (int mk = 1; mk < 64; mk <<= 1) s += __shfl_xor(s, mk, 64);
  if (lane == 0) e2c[row] = (float)(s - 1024.0);
}

// ---------------- deep-pipelined split GEMM (256x128 tile, BK=32, 3-buf) ----------------
// MODE 0: tokens epilogue (bias, hi/lo split, ||t||^2)   vec=b_in
// MODE 1: score epilogue (argmin -> packed atomicMin)    vec=e2c
template <int KDIM, int MODE, int LOG_GX>
__global__ __launch_bounds__(512, 2) void k_gemm_split(
    const _Float16* __restrict__ Ah_, const _Float16* __restrict__ Al_,
    const _Float16* __restrict__ Bh_, const _Float16* __restrict__ Bl_,
    const float* __restrict__ vec,
    _Float16* __restrict__ outh, _Float16* __restrict__ outl,
    float* __restrict__ t2, unsigned long long* __restrict__ keys) {
  // stage = 48KB: Ah[256x32] @0, Al @16384B, Bh[128x32] @32768B, Bl @40960B
  __shared__ _Float16 lds[3 * 24576];

  // bijective XCD swizzle (nwg % 8 == 0 for both launches)
  const int nwg = gridDim.x;
  const int bid = blockIdx.x;
  const int q = nwg >> 3;
  const int b2 = (bid & 7) * q + (bid >> 3);
  const int n0 = (b2 & ((1 << LOG_GX) - 1)) * 128;
  const int m0 = (b2 >> LOG_GX) * 256;

  const int tid = threadIdx.x, lane = tid & 63, w = tid >> 6;
  const int wr = w >> 1, wc = w & 1, lr = lane & 15, lk = lane >> 4;
  constexpr int NT = KDIM / 32;

  f32x4 acc[4][4] = {};

  auto stageA2 = [&](const _Float16* __restrict__ src, int k0, char* regionBase) {
    int slot0 = w * 64 + lane;
    gload16(src + (size_t)(m0 + (slot0 >> 2)) * KDIM + k0 + (slot0 & 3) * 8,
            regionBase + w * 1024);
    int slot1 = slot0 + 512;
    gload16(src + (size_t)(m0 + (slot1 >> 2)) * KDIM + k0 + (slot1 & 3) * 8,
            regionBase + w * 1024 + 8192);
  };
  auto stageB2 = [&](int k0, char* stageBase) {
    int slot = w * 64 + lane;
    size_t go = (size_t)(n0 + (slot >> 2)) * KDIM + k0 + (slot & 3) * 8;
    gload16(Bh_ + go, stageBase + 32768 + w * 1024);
    gload16(Bl_ + go, stageBase + 40960 + w * 1024);
  };
  auto stageAll = [&](int t, int c) {  // 6 loads
    char* sb = (char*)lds + c * 49152;
    stageA2(Ah_, t * 32, sb);
    stageA2(Al_, t * 32, sb + 16384);
    stageB2(t * 32, sb);
  };

  // prologue: stage tiles 0 and 1, wait for tile 0
  stageAll(0, 0);
  stageAll(1, 1);
  WAITV6();
  SBAR();

  int c0 = 0, c1 = 1, c2 = 2;
  for (int t = 0; t < NT; ++t) {
    const _Float16* sb = lds + c0 * 24576;
    char* dstb = (char*)lds + c2 * 49152;
    const bool st = (t + 2) < NT;
    const int ks = (t + 2) * 32;
    half8 ah[4], bh[4], al[4], bl[4];

    // ---- phase 1: read ah,bh ; prefetch Ah(t+2) ; MFMA hh ----
#pragma unroll
    for (int f = 0; f < 4; ++f) {
      ah[f] = *(const half8*)(sb + (wr * 64 + f * 16 + lr) * 32 + lk * 8);
      bh[f] = *(const half8*)(sb + 16384 + (wc * 64 + f * 16 + lr) * 32 + lk * 8);
    }
    if (st) stageA2(Ah_, ks, dstb);
    SBAR();
    __builtin_amdgcn_s_setprio(1);
#pragma unroll
    for (int fm = 0; fm < 4; ++fm)
#pragma unroll
      for (int fn = 0; fn < 4; ++fn)
        acc[fm][fn] = __builtin_amdgcn_mfma_f32_16x16x32_f16(ah[fm], bh[fn], acc[fm][fn], 0, 0, 0);
    __builtin_amdgcn_s_setprio(0);
    SBAR();

    // ---- phase 2: read bl ; prefetch Al(t+2) ; MFMA h*lo ----
#pragma unroll
    for (int f = 0; f < 4; ++f)
      bl[f] = *(const half8*)(sb + 20480 + (wc * 64 + f * 16 + lr) * 32 + lk * 8);
    if (st) stageA2(Al_, ks, dstb + 16384);
    SBAR();
    __builtin_amdgcn_s_setprio(1);
#pragma unroll
    for (int fm = 0; fm < 4; ++fm)
#pragma unroll
      for (int fn = 0; fn < 4; ++fn)
        acc[fm][fn] = __builtin_amdgcn_mfma_f32_16x16x32_f16(ah[fm], bl[fn], acc[fm][fn], 0, 0, 0);
    __builtin_amdgcn_s_setprio(0);
    SBAR();

    // ---- phase 3: read al ; prefetch Bh/Bl(t+2) ; MFMA lo*h ; counted vmcnt ----
#pragma unroll
    for (int f = 0; f < 4; ++f)
      al[f] = *(const half8*)(sb + 8192 + (wr * 64 + f * 16 + lr) * 32 + lk * 8);
    if (st) stageB2(ks, dstb);
    SBAR();
    __builtin_amdgcn_s_setprio(1);
#pragma unroll
    for (int fm = 0; fm < 4; ++fm)
#pragma unroll
      for (int fn = 0; fn < 4; ++fn)
        acc[fm][fn] = __builtin_amdgcn_mfma_f32_16x16x32_f16(al[fm], bh[fn], acc[fm][fn], 0, 0, 0);
    __builtin_amdgcn_s_setprio(0);
    if (st) { WAITV6(); } else if (t + 1 < NT) { WAITV0(); }
    SBAR();

    int tmp = c0; c0 = c1; c1 = c2; c2 = tmp;
  }

  if constexpr (MODE == 0) {
    // epilogue: +b_in, split to f16 hi/lo, accumulate ||t||^2 per token row
#pragma unroll
    for (int fm = 0; fm < 4; ++fm) {
#pragma unroll
      for (int j = 0; j < 4; ++j) {
        int row = wr * 64 + fm * 16 + lk * 4 + j;
        size_t m = (size_t)m0 + row;
        float v2 = 0.f;
#pragma unroll
        for (int fn = 0; fn < 4; ++fn) {
          int col = n0 + wc * 64 + fn * 16 + lr;
          float v = acc[fm][fn][j] + vec[col];
          v2 += v * v;
          _Float16 h = (_Float16)v;
          outh[m * D + col] = h;
          outl[m * D + col] = (_Float16)(v - (float)h);
        }
#pragma unroll
        for (int mk = 1; mk < 16; mk <<= 1) v2 += __shfl_xor(v2, mk, 64);
        if (lr == 0) atomicAdd(&t2[m], v2);
      }
    }
  } else {
    // epilogue: mval = (||e||^2 - 1024) - 2*score; wave-local argmin -> packed atomicMin
#pragma unroll
    for (int fm = 0; fm < 4; ++fm) {
#pragma unroll
      for (int j = 0; j < 4; ++j) {
        int row = wr * 64 + fm * 16 + lk * 4 + j;
        size_t m = (size_t)m0 + row;
        float best = 3.4e38f;
        int bidx = 0x7FFFFFFF;
#pragma unroll
        for (int fn = 0; fn < 4; ++fn) {
          int col = n0 + wc * 64 + fn * 16 + lr;
          float mv = vec[col] - 2.0f * acc[fm][fn][j];
          if (mv < best) { best = mv; bidx = col; }
        }
#pragma unroll
        for (int mk = 1; mk < 16; mk <<= 1) {
          float ob = __shfl_xor(best, mk, 64);
          int oi = __shfl_xor(bidx, mk, 64);
          if (ob < best || (ob == best && oi < bidx)) { best = ob; bidx = oi; }
        }
        if (lr == 0) {
          unsigned ub = __float_as_uint(best);
          ub = (ub & 0x80000000u) ? ~ub : (ub | 0x80000000u);
          unsigned long long key = ((unsigned long long)ub << 32) | (unsigned)bidx;
          atomicMin(&keys[m], key);
        }
      }
    }
  }
}

// ---------------- GEMM C: out = embed[idx] * w_out^T (unchanged) ----------------
__global__ __launch_bounds__(256) void k_gemm_out(
    const _Float16* __restrict__ eh, const unsigned long long* __restrict__ keys,
    const _Float16* __restrict__ woh, const float* __restrict__ b_out,
    const float* __restrict__ mask, float* __restrict__ out) {
  __shared__ _Float16 sA[128 * 32], sB[128 * 32];
  __shared__ float sC[32 * 129];
  const int n0 = blockIdx.x * 128, m0 = blockIdx.y * 128;
  const int tid = threadIdx.x, lane = tid & 63, w = tid >> 6;
  const int wr = w >> 1, wc = w & 1, lr = lane & 15, lk = lane >> 4;
  f32x4 acc[4][4] = {};

  const int g0 = w * 128 + lane, g1 = g0 + 64;
  const int rA0 = g0 >> 2, cA0 = g0 & 3, rA1 = g1 >> 2, cA1 = g1 & 3;
  const int lb0 = (w * 128) * 16, lb1 = (w * 128 + 64) * 16;
  const unsigned i0 = (unsigned)(keys[m0 + rA0] & 0xFFFFFFFFull);
  const unsigned i1 = (unsigned)(keys[m0 + rA1] & 0xFFFFFFFFull);
  const _Float16* srcA0 = eh + (size_t)i0 * D + cA0 * 8;
  const _Float16* srcA1 = eh + (size_t)i1 * D + cA1 * 8;

  for (int kt = 0; kt < D / 32; ++kt) {
    const int k0 = kt * 32;
    gload16(srcA0 + k0, (char*)sA + lb0);
    gload16(srcA1 + k0, (char*)sA + lb1);
    gload16(woh + (size_t)(n0 + rA0) * D + k0 + cA0 * 8, (char*)sB + lb0);
    gload16(woh + (size_t)(n0 + rA1) * D + k0 + cA1 * 8, (char*)sB + lb1);
    __syncthreads();
    half8 a[4], b[4];
#pragma unroll
    for (int f = 0; f < 4; ++f) {
      a[f] = *(const half8*)(sA + (wr * 64 + f * 16 + lr) * 32 + lk * 8);
      b[f] = *(const half8*)(sB + (wc * 64 + f * 16 + lr) * 32 + lk * 8);
    }
#pragma unroll
    for (int fm = 0; fm < 4; ++fm)
#pragma unroll
      for (int fn = 0; fn < 4; ++fn)
        acc[fm][fn] = __builtin_amdgcn_mfma_f32_16x16x32_f16(a[fm], b[fn], acc[fm][fn], 0, 0, 0);
    __syncthreads();
  }
  for (int ch = 0; ch < 4; ++ch) {
    __syncthreads();
    if (wr == (ch >> 1)) {
      int fb = (ch & 1) * 2;
#pragma unroll
      for (int f2 = 0; f2 < 2; ++f2) {
        int fm = fb + f2;
#pragma unroll
        for (int fn = 0; fn < 4; ++fn)
#pragma unroll
          for (int j = 0; j < 4; ++j) {
            int lrow = f2 * 16 + lk * 4 + j;
            int col = wc * 64 + fn * 16 + lr;
            sC[lrow * 129 + col] = acc[fm][fn][j] + b_out[n0 + col];
          }
      }
    }
    __syncthreads();
    const int mbase = m0 + ch * 32;
    const int b = mbase >> 11;
    const int l0 = mbase & 2047;
    const float mval = mask[(size_t)b * TLEN + 2 * l0 + lane];
    for (int oo = 0; oo < 32; ++oo) {
      int ocol = w * 32 + oo;
      float v = sC[(lane >> 1) * 129 + ocol];
      out[((size_t)(b * D + n0 + ocol)) * TLEN + 2 * l0 + lane] = v * mval;
    }
  }
}

// ---------------- loss ----------------
__global__ __launch_bounds__(256) void k_loss(const unsigned long long* __restrict__ keys,
                                              const float* __restrict__ t2,
                                              double* __restrict__ acc) {
  int m = blockIdx.x * 256 + threadIdx.x;
  unsigned long long k = keys[m];
  unsigned u = (unsigned)(k >> 32);
  unsigned bits = (u & 0x80000000u) ? (u & 0x7FFFFFFFu) : ~u;
  float mval = __uint_as_float(bits);
  double c = (double)mval + 1024.0 + (double)t2[m];
#pragma unroll
  for (int mk = 1; mk < 64; mk <<= 1) c += __shfl_xor(c, mk, 64);
  __shared__ double part[4];
  if ((threadIdx.x & 63) == 0) part[threadIdx.x >> 6] = c;
  __syncthreads();
  if (threadIdx.x == 0) atomicAdd(acc, part[0] + part[1] + part[2] + part[3]);
}

__global__ void k_finalize(const double* __restrict__ acc, float* __restrict__ dst) {
  if (threadIdx.x == 0 && blockIdx.x == 0) *dst = (float)(*acc * (1.0 / 16777216.0));
}

// ---------------- host ----------------
extern "C" void kernel_launch(void* const* d_in, const int* in_sizes, int n_in,
                              void* d_out, int out_size, void* d_ws, size_t ws_size,
                              hipStream_t stream) {
  (void)in_sizes; (void)n_in; (void)out_size;
  const float* x      = (const float*)d_in[0];
  const float* xmask  = (const float*)d_in[1];
  const float* w_in   = (const float*)d_in[2];
  const float* b_in   = (const float*)d_in[3];
  const float* embed  = (const float*)d_in[4];
  const float* w_out  = (const float*)d_in[5];
  const float* b_out  = (const float*)d_in[6];
  float* out = (float*)d_out;

  _Float16* xh = (_Float16*)d_out;
  _Float16* xl = xh + (size_t)MTOK * KIN;

  char* p = (char*)d_ws;
  auto take = [&](size_t sz) { char* r = p; p += (sz + 255) & ~(size_t)255; return r; };
  _Float16* wh   = (_Float16*)take((size_t)D * KIN * 2);
  _Float16* wl   = (_Float16*)take((size_t)D * KIN * 2);
  _Float16* eh   = (_Float16*)take((size_t)NCODE * D * 2);
  _Float16* el   = (_Float16*)take((size_t)NCODE * D * 2);
  _Float16* woh  = (_Float16*)take((size_t)D * D * 2);
  float* e2c     = (float*)take((size_t)NCODE * 4);
  _Float16* tokh = (_Float16*)take((size_t)MTOK * D * 2);
  _Float16* tokl = (_Float16*)take((size_t)MTOK * D * 2);
  float* t2      = (float*)take((size_t)MTOK * 4);
  unsigned long long* keys = (unsigned long long*)take((size_t)MTOK * 8);
  double* lossacc = (double*)take(256);
  if ((size_t)(p - (char*)d_ws) > ws_size) return;

  hipMemsetAsync(keys, 0xFF, (size_t)MTOK * 8, stream);
  hipMemsetAsync(t2, 0, (size_t)MTOK * 4, stream);
  hipMemsetAsync(lossacc, 0, 8, stream);

  k_pack_x<<<dim3(64, 32, 8), 256, 0, stream>>>(x, xh, xl);
  k_split<<<(D * KIN + 255) / 256, 256, 0, stream>>>(w_in, wh, wl, D * KIN);
  k_split<<<(NCODE * D + 255) / 256, 256, 0, stream>>>(embed, eh, el, NCODE * D);
  k_tohalf<<<(D * D + 255) / 256, 256, 0, stream>>>(w_out, woh, D * D);
  k_e2<<<NCODE / 4, 256, 0, stream>>>(embed, e2c);

  // tok GEMM: M=16384 (64 m-blocks of 256), N=1024 (8 n-blocks of 128) -> 512 blocks
  k_gemm_split<KIN, 0, 3><<<512, 512, 0, stream>>>(xh, xl, wh, wl, b_in,
                                                   tokh, tokl, t2, nullptr);
  // score GEMM: M=16384, N=2048 (16 n-blocks) -> 1024 blocks
  k_gemm_split<D, 1, 4><<<1024, 512, 0, stream>>>(tokh, tokl, eh, el, e2c,
                                                  nullptr, nullptr, nullptr, keys);

  k_gemm_out<<<dim3(D / 128, MTOK / 128), 256, 0, stream>>>(eh, keys, woh, b_out, xmask, out);

  k_loss<<<MTOK / 256, 256, 0, stream>>>(keys, t2, lossacc);
  k_finalize<<<1, 64, 0, stream>>>(lossacc, out + (size_t)MTOK * KIN);
}

// Round 3
// 555.711 us; speedup vs baseline: 1.0729x; 1.0233x over previous
//
#include <hip/hip_runtime.h>

typedef _Float16 half8 __attribute__((ext_vector_type(8)));
typedef float f32x4 __attribute__((ext_vector_type(4)));

static constexpr int D = 1024;       // VQ_C == C_IN
static constexpr int NCODE = 2048;   // codebook size
static constexpr int MTOK = 16384;   // B * L = 8 * 2048
static constexpr int KIN = 2048;     // C_IN * DS
static constexpr int TLEN = 4096;

__device__ __forceinline__ void gload16(const void* g, void* l) {
  __builtin_amdgcn_global_load_lds(
      (const __attribute__((address_space(1))) void*)g,
      (__attribute__((address_space(3))) void*)l, 16, 0, 0);
}

#define SBAR()   asm volatile("s_barrier" ::: "memory")
#define WAITV6() asm volatile("s_waitcnt vmcnt(6)" ::: "memory")
#define WAITV0() asm volatile("s_waitcnt vmcnt(0)" ::: "memory")

// ---------------- pack kernels (unchanged) ----------------
__global__ __launch_bounds__(256) void k_pack_x(const float* __restrict__ x,
                                                _Float16* __restrict__ xh,
                                                _Float16* __restrict__ xl) {
  __shared__ float lds[32][65];
  const int tt0 = blockIdx.x * 64;
  const int cc0 = blockIdx.y * 32;
  const int b = blockIdx.z;
  const float* xb = x + ((size_t)b * D + cc0) * TLEN + tt0;
#pragma unroll
  for (int i = 0; i < 8; ++i) {
    int idx = threadIdx.x + i * 256;
    lds[idx >> 6][idx & 63] = xb[(size_t)(idx >> 6) * TLEN + (idx & 63)];
  }
  __syncthreads();
  const size_t mrow0 = (size_t)b * 2048 + (tt0 >> 1);
#pragma unroll
  for (int i = 0; i < 8; ++i) {
    int idx = threadIdx.x + i * 256;
    int r = idx >> 6, kk = idx & 63;
    float v = lds[kk >> 1][2 * r + (kk & 1)];
    _Float16 h = (_Float16)v;
    size_t off = (mrow0 + r) * (size_t)KIN + (size_t)cc0 * 2 + kk;
    xh[off] = h;
    xl[off] = (_Float16)(v - (float)h);
  }
}

__global__ __launch_bounds__(256) void k_split(const float* __restrict__ s,
                                               _Float16* __restrict__ hi,
                                               _Float16* __restrict__ lo, int n) {
  int i = blockIdx.x * 256 + threadIdx.x;
  if (i < n) {
    float v = s[i];
    _Float16 h = (_Float16)v;
    hi[i] = h;
    lo[i] = (_Float16)(v - (float)h);
  }
}

__global__ __launch_bounds__(256) void k_tohalf(const float* __restrict__ s,
                                                _Float16* __restrict__ hi, int n) {
  int i = blockIdx.x * 256 + threadIdx.x;
  if (i < n) hi[i] = (_Float16)s[i];
}

__global__ __launch_bounds__(256) void k_e2(const float* __restrict__ embed,
                                            float* __restrict__ e2c) {
  int row = blockIdx.x * 4 + (threadIdx.x >> 6);
  int lane = threadIdx.x & 63;
  const float* er = embed + (size_t)row * D;
  double s = 0.0;
  for (int i = lane; i < D; i += 64) { double v = er[i]; s += v * v; }
#pragma unroll
  for (int mk = 1; mk < 64; mk <<= 1) s += __shfl_xor(s, mk, 64);
  if (lane == 0) e2c[row] = (float)(s - 1024.0);
}

// ---------------- deep-pipelined split GEMM (256x128 tile, BK=32, 3-buf) ----------------
// T2 chunk-XOR swizzle: within each 64B row, chunk' = chunk ^ ((row>>1)&3).
// gload_lds writes LDS linearly, so the GLOBAL source chunk is pre-swizzled
// (write-side XOR is lane-constant: (lane&3)^((lane>>3)&3)); the ds_read applies
// the same involution (read-side XOR is lane-constant: lk^((lr>>1)&3)).
// MODE 0: tokens epilogue (bias, hi/lo split, ||t||^2)   vec=b_in
// MODE 1: score epilogue (argmin -> packed atomicMin)    vec=e2c
template <int KDIM, int MODE, int LOG_GX>
__global__ __launch_bounds__(512, 2) void k_gemm_split(
    const _Float16* __restrict__ Ah_, const _Float16* __restrict__ Al_,
    const _Float16* __restrict__ Bh_, const _Float16* __restrict__ Bl_,
    const float* __restrict__ vec,
    _Float16* __restrict__ outh, _Float16* __restrict__ outl,
    float* __restrict__ t2, unsigned long long* __restrict__ keys) {
  // stage = 48KB: Ah[256x32] @0, Al @16384B, Bh[128x32] @32768B, Bl @40960B
  __shared__ _Float16 lds[3 * 24576];

  // bijective XCD swizzle (nwg % 8 == 0 for both launches)
  const int nwg = gridDim.x;
  const int bid = blockIdx.x;
  const int q = nwg >> 3;
  const int b2 = (bid & 7) * q + (bid >> 3);
  const int n0 = (b2 & ((1 << LOG_GX) - 1)) * 128;
  const int m0 = (b2 >> LOG_GX) * 256;

  const int tid = threadIdx.x, lane = tid & 63, w = tid >> 6;
  const int wr = w >> 1, wc = w & 1, lr = lane & 15, lk = lane >> 4;
  constexpr int NT = KDIM / 32;

  // swizzle constants (both lane-constant)
  const int cswz8 = (((lane & 3) ^ ((lane >> 3) & 3))) * 8;   // global-side, half units
  const int rswz8 = (lk ^ ((lr >> 1) & 3)) * 8;               // read-side, half units

  f32x4 acc[4][4] = {};

  auto stageA2 = [&](const _Float16* __restrict__ src, int k0, char* regionBase) {
    int slot0 = w * 64 + lane;
    gload16(src + (size_t)(m0 + (slot0 >> 2)) * KDIM + k0 + cswz8,
            regionBase + w * 1024);
    int slot1 = slot0 + 512;
    gload16(src + (size_t)(m0 + (slot1 >> 2)) * KDIM + k0 + cswz8,
            regionBase + w * 1024 + 8192);
  };
  auto stageB2 = [&](int k0, char* stageBase) {
    int slot = w * 64 + lane;
    size_t go = (size_t)(n0 + (slot >> 2)) * KDIM + k0 + cswz8;
    gload16(Bh_ + go, stageBase + 32768 + w * 1024);
    gload16(Bl_ + go, stageBase + 40960 + w * 1024);
  };
  auto stageAll = [&](int t, int c) {  // 6 loads
    char* sb = (char*)lds + c * 49152;
    stageA2(Ah_, t * 32, sb);
    stageA2(Al_, t * 32, sb + 16384);
    stageB2(t * 32, sb);
  };

  // prologue: stage tiles 0 and 1, wait for tile 0
  stageAll(0, 0);
  stageAll(1, 1);
  WAITV6();
  SBAR();

  int c0 = 0, c1 = 1, c2 = 2;
  for (int t = 0; t < NT; ++t) {
    const _Float16* sb = lds + c0 * 24576;
    char* dstb = (char*)lds + c2 * 49152;
    const bool st = (t + 2) < NT;
    const int ks = (t + 2) * 32;
    half8 ah[4], bh[4], al[4], bl[4];

    // ---- phase 1: read ah,bh ; prefetch Ah(t+2) ; MFMA hh ----
#pragma unroll
    for (int f = 0; f < 4; ++f) {
      ah[f] = *(const half8*)(sb + (wr * 64 + f * 16 + lr) * 32 + rswz8);
      bh[f] = *(const half8*)(sb + 16384 + (wc * 64 + f * 16 + lr) * 32 + rswz8);
    }
    if (st) stageA2(Ah_, ks, dstb);
    SBAR();
    __builtin_amdgcn_s_setprio(1);
#pragma unroll
    for (int fm = 0; fm < 4; ++fm)
#pragma unroll
      for (int fn = 0; fn < 4; ++fn)
        acc[fm][fn] = __builtin_amdgcn_mfma_f32_16x16x32_f16(ah[fm], bh[fn], acc[fm][fn], 0, 0, 0);
    __builtin_amdgcn_s_setprio(0);
    SBAR();

    // ---- phase 2: read bl ; prefetch Al(t+2) ; MFMA h*lo ----
#pragma unroll
    for (int f = 0; f < 4; ++f)
      bl[f] = *(const half8*)(sb + 20480 + (wc * 64 + f * 16 + lr) * 32 + rswz8);
    if (st) stageA2(Al_, ks, dstb + 16384);
    SBAR();
    __builtin_amdgcn_s_setprio(1);
#pragma unroll
    for (int fm = 0; fm < 4; ++fm)
#pragma unroll
      for (int fn = 0; fn < 4; ++fn)
        acc[fm][fn] = __builtin_amdgcn_mfma_f32_16x16x32_f16(ah[fm], bl[fn], acc[fm][fn], 0, 0, 0);
    __builtin_amdgcn_s_setprio(0);
    SBAR();

    // ---- phase 3: read al ; prefetch Bh/Bl(t+2) ; MFMA lo*h ; counted vmcnt ----
#pragma unroll
    for (int f = 0; f < 4; ++f)
      al[f] = *(const half8*)(sb + 8192 + (wr * 64 + f * 16 + lr) * 32 + rswz8);
    if (st) stageB2(ks, dstb);
    SBAR();
    __builtin_amdgcn_s_setprio(1);
#pragma unroll
    for (int fm = 0; fm < 4; ++fm)
#pragma unroll
      for (int fn = 0; fn < 4; ++fn)
        acc[fm][fn] = __builtin_amdgcn_mfma_f32_16x16x32_f16(al[fm], bh[fn], acc[fm][fn], 0, 0, 0);
    __builtin_amdgcn_s_setprio(0);
    if (st) { WAITV6(); } else if (t + 1 < NT) { WAITV0(); }
    SBAR();

    int tmp = c0; c0 = c1; c1 = c2; c2 = tmp;
  }

  if constexpr (MODE == 0) {
    // epilogue: +b_in, split to f16 hi/lo, accumulate ||t||^2 per token row
#pragma unroll
    for (int fm = 0; fm < 4; ++fm) {
#pragma unroll
      for (int j = 0; j < 4; ++j) {
        int row = wr * 64 + fm * 16 + lk * 4 + j;
        size_t m = (size_t)m0 + row;
        float v2 = 0.f;
#pragma unroll
        for (int fn = 0; fn < 4; ++fn) {
          int col = n0 + wc * 64 + fn * 16 + lr;
          float v = acc[fm][fn][j] + vec[col];
          v2 += v * v;
          _Float16 h = (_Float16)v;
          outh[m * D + col] = h;
          outl[m * D + col] = (_Float16)(v - (float)h);
        }
#pragma unroll
        for (int mk = 1; mk < 16; mk <<= 1) v2 += __shfl_xor(v2, mk, 64);
        if (lr == 0) atomicAdd(&t2[m], v2);
      }
    }
  } else {
    // epilogue: mval = (||e||^2 - 1024) - 2*score; wave-local argmin -> packed atomicMin
#pragma unroll
    for (int fm = 0; fm < 4; ++fm) {
#pragma unroll
      for (int j = 0; j < 4; ++j) {
        int row = wr * 64 + fm * 16 + lk * 4 + j;
        size_t m = (size_t)m0 + row;
        float best = 3.4e38f;
        int bidx = 0x7FFFFFFF;
#pragma unroll
        for (int fn = 0; fn < 4; ++fn) {
          int col = n0 + wc * 64 + fn * 16 + lr;
          float mv = vec[col] - 2.0f * acc[fm][fn][j];
          if (mv < best) { best = mv; bidx = col; }
        }
#pragma unroll
        for (int mk = 1; mk < 16; mk <<= 1) {
          float ob = __shfl_xor(best, mk, 64);
          int oi = __shfl_xor(bidx, mk, 64);
          if (ob < best || (ob == best && oi < bidx)) { best = ob; bidx = oi; }
        }
        if (lr == 0) {
          unsigned ub = __float_as_uint(best);
          ub = (ub & 0x80000000u) ? ~ub : (ub | 0x80000000u);
          unsigned long long key = ((unsigned long long)ub << 32) | (unsigned)bidx;
          atomicMin(&keys[m], key);
        }
      }
    }
  }
}

// ---------------- GEMM C: out = embed[idx] * w_out^T (unchanged) ----------------
__global__ __launch_bounds__(256) void k_gemm_out(
    const _Float16* __restrict__ eh, const unsigned long long* __restrict__ keys,
    const _Float16* __restrict__ woh, const float* __restrict__ b_out,
    const float* __restrict__ mask, float* __restrict__ out) {
  __shared__ _Float16 sA[128 * 32], sB[128 * 32];
  __shared__ float sC[32 * 129];
  const int n0 = blockIdx.x * 128, m0 = blockIdx.y * 128;
  const int tid = threadIdx.x, lane = tid & 63, w = tid >> 6;
  const int wr = w >> 1, wc = w & 1, lr = lane & 15, lk = lane >> 4;
  f32x4 acc[4][4] = {};

  const int g0 = w * 128 + lane, g1 = g0 + 64;
  const int rA0 = g0 >> 2, cA0 = g0 & 3, rA1 = g1 >> 2, cA1 = g1 & 3;
  const int lb0 = (w * 128) * 16, lb1 = (w * 128 + 64) * 16;
  const unsigned i0 = (unsigned)(keys[m0 + rA0] & 0xFFFFFFFFull);
  const unsigned i1 = (unsigned)(keys[m0 + rA1] & 0xFFFFFFFFull);
  const _Float16* srcA0 = eh + (size_t)i0 * D + cA0 * 8;
  const _Float16* srcA1 = eh + (size_t)i1 * D + cA1 * 8;

  for (int kt = 0; kt < D / 32; ++kt) {
    const int k0 = kt * 32;
    gload16(srcA0 + k0, (char*)sA + lb0);
    gload16(srcA1 + k0, (char*)sA + lb1);
    gload16(woh + (size_t)(n0 + rA0) * D + k0 + cA0 * 8, (char*)sB + lb0);
    gload16(woh + (size_t)(n0 + rA1) * D + k0 + cA1 * 8, (char*)sB + lb1);
    __syncthreads();
    half8 a[4], b[4];
#pragma unroll
    for (int f = 0; f < 4; ++f) {
      a[f] = *(const half8*)(sA + (wr * 64 + f * 16 + lr) * 32 + lk * 8);
      b[f] = *(const half8*)(sB + (wc * 64 + f * 16 + lr) * 32 + lk * 8);
    }
#pragma unroll
    for (int fm = 0; fm < 4; ++fm)
#pragma unroll
      for (int fn = 0; fn < 4; ++fn)
        acc[fm][fn] = __builtin_amdgcn_mfma_f32_16x16x32_f16(a[fm], b[fn], acc[fm][fn], 0, 0, 0);
    __syncthreads();
  }
  for (int ch = 0; ch < 4; ++ch) {
    __syncthreads();
    if (wr == (ch >> 1)) {
      int fb = (ch & 1) * 2;
#pragma unroll
      for (int f2 = 0; f2 < 2; ++f2) {
        int fm = fb + f2;
#pragma unroll
        for (int fn = 0; fn < 4; ++fn)
#pragma unroll
          for (int j = 0; j < 4; ++j) {
            int lrow = f2 * 16 + lk * 4 + j;
            int col = wc * 64 + fn * 16 + lr;
            sC[lrow * 129 + col] = acc[fm][fn][j] + b_out[n0 + col];
          }
      }
    }
    __syncthreads();
    const int mbase = m0 + ch * 32;
    const int b = mbase >> 11;
    const int l0 = mbase & 2047;
    const float mval = mask[(size_t)b * TLEN + 2 * l0 + lane];
    for (int oo = 0; oo < 32; ++oo) {
      int ocol = w * 32 + oo;
      float v = sC[(lane >> 1) * 129 + ocol];
      out[((size_t)(b * D + n0 + ocol)) * TLEN + 2 * l0 + lane] = v * mval;
    }
  }
}

// ---------------- loss ----------------
__global__ __launch_bounds__(256) void k_loss(const unsigned long long* __restrict__ keys,
                                              const float* __restrict__ t2,
                                              double* __restrict__ acc) {
  int m = blockIdx.x * 256 + threadIdx.x;
  unsigned long long k = keys[m];
  unsigned u = (unsigned)(k >> 32);
  unsigned bits = (u & 0x80000000u) ? (u & 0x7FFFFFFFu) : ~u;
  float mval = __uint_as_float(bits);
  double c = (double)mval + 1024.0 + (double)t2[m];
#pragma unroll
  for (int mk = 1; mk < 64; mk <<= 1) c += __shfl_xor(c, mk, 64);
  __shared__ double part[4];
  if ((threadIdx.x & 63) == 0) part[threadIdx.x >> 6] = c;
  __syncthreads();
  if (threadIdx.x == 0) atomicAdd(acc, part[0] + part[1] + part[2] + part[3]);
}

__global__ void k_finalize(const double* __restrict__ acc, float* __restrict__ dst) {
  if (threadIdx.x == 0 && blockIdx.x == 0) *dst = (float)(*acc * (1.0 / 16777216.0));
}

// ---------------- host ----------------
extern "C" void kernel_launch(void* const* d_in, const int* in_sizes, int n_in,
                              void* d_out, int out_size, void* d_ws, size_t ws_size,
                              hipStream_t stream) {
  (void)in_sizes; (void)n_in; (void)out_size;
  const float* x      = (const float*)d_in[0];
  const float* xmask  = (const float*)d_in[1];
  const float* w_in   = (const float*)d_in[2];
  const float* b_in   = (const float*)d_in[3];
  const float* embed  = (const float*)d_in[4];
  const float* w_out  = (const float*)d_in[5];
  const float* b_out  = (const float*)d_in[6];
  float* out = (float*)d_out;

  _Float16* xh = (_Float16*)d_out;
  _Float16* xl = xh + (size_t)MTOK * KIN;

  char* p = (char*)d_ws;
  auto take = [&](size_t sz) { char* r = p; p += (sz + 255) & ~(size_t)255; return r; };
  _Float16* wh   = (_Float16*)take((size_t)D * KIN * 2);
  _Float16* wl   = (_Float16*)take((size_t)D * KIN * 2);
  _Float16* eh   = (_Float16*)take((size_t)NCODE * D * 2);
  _Float16* el   = (_Float16*)take((size_t)NCODE * D * 2);
  _Float16* woh  = (_Float16*)take((size_t)D * D * 2);
  float* e2c     = (float*)take((size_t)NCODE * 4);
  _Float16* tokh = (_Float16*)take((size_t)MTOK * D * 2);
  _Float16* tokl = (_Float16*)take((size_t)MTOK * D * 2);
  float* t2      = (float*)take((size_t)MTOK * 4);
  unsigned long long* keys = (unsigned long long*)take((size_t)MTOK * 8);
  double* lossacc = (double*)take(256);
  if ((size_t)(p - (char*)d_ws) > ws_size) return;

  hipMemsetAsync(keys, 0xFF, (size_t)MTOK * 8, stream);
  hipMemsetAsync(t2, 0, (size_t)MTOK * 4, stream);
  hipMemsetAsync(lossacc, 0, 8, stream);

  k_pack_x<<<dim3(64, 32, 8), 256, 0, stream>>>(x, xh, xl);
  k_split<<<(D * KIN + 255) / 256, 256, 0, stream>>>(w_in, wh, wl, D * KIN);
  k_split<<<(NCODE * D + 255) / 256, 256, 0, stream>>>(embed, eh, el, NCODE * D);
  k_tohalf<<<(D * D + 255) / 256, 256, 0, stream>>>(w_out, woh, D * D);
  k_e2<<<NCODE / 4, 256, 0, stream>>>(embed, e2c);

  // tok GEMM: M=16384 (64 m-blocks of 256), N=1024 (8 n-blocks of 128) -> 512 blocks
  k_gemm_split<KIN, 0, 3><<<512, 512, 0, stream>>>(xh, xl, wh, wl, b_in,
                                                   tokh, tokl, t2, nullptr);
  // score GEMM: M=16384, N=2048 (16 n-blocks) -> 1024 blocks
  k_gemm_split<D, 1, 4><<<1024, 512, 0, stream>>>(tokh, tokl, eh, el, e2c,
                                                  nullptr, nullptr, nullptr, keys);

  k_gemm_out<<<dim3(D / 128, MTOK / 128), 256, 0, stream>>>(eh, keys, woh, b_out, xmask, out);

  k_loss<<<MTOK / 256, 256, 0, stream>>>(keys, t2, lossacc);
  k_finalize<<<1, 64, 0, stream>>>(lossacc, out + (size_t)MTOK * KIN);
}